// Round 12
// baseline (37.447 us; speedup 1.0000x reference)
//
#include <hip/hip_runtime.h>
#include <math.h>

// SeesawLoss forward: B=8192 rows, C=4096 classes, P=0.8, Q=2.0, EPS=0.01
// Log-space algebra (no M2, no pass-3 transcendentals):
//   L    = logsumexp(o) ;  Koff = L + max(o_t - L, log(EPS))
//   g_j  = exp(o_j - Koff)  (= sratio_j);  exp(logit_j - Koff) = mit_j*max(g^3,g)
//   mit_j = min(powacc_j/powacc_t, 1)   [powacc = acc^0.8, monotone -> pred ok]
//   nll_b = Koff + log(Z) - o_t,  Z = sum_j mit_j*max(g_j^3, g_j)
// Range-safe: g <= 100 -> Z <= 4e9; Z >= g_t > 0. j==t term = g_t (mask-free).
//
// This round: 128-thread blocks, 32 floats/thread in 8 NAMED float4s (32 data
// VGPR; R8 showed 64 data VGPR spills). Barriers span 2 waves; 16 blocks/CU
// for finer phase stagger. powacc loaded inline in pass 3 (L2-hot) to keep
// VGPR <= 64 under __launch_bounds__(128,8). NO grid-wide atomics and NO
// cooperative grid.sync (R4/R5: same-line atomic+fence across 8 XCDs ~670us).

#define CC 4096

__device__ __forceinline__ float wave_max(float v) {
    #pragma unroll
    for (int o = 32; o > 0; o >>= 1) v = fmaxf(v, __shfl_xor(v, o, 64));
    return v;
}
__device__ __forceinline__ float wave_sum(float v) {
    #pragma unroll
    for (int o = 32; o > 0; o >>= 1) v += __shfl_xor(v, o, 64);
    return v;
}

// exp each component against lane max (in place), return component sum
__device__ __forceinline__ float exp4(float4& v, float m) {
    v.x = __expf(v.x - m); v.y = __expf(v.y - m);
    v.z = __expf(v.z - m); v.w = __expf(v.w - m);
    return (v.x + v.y) + (v.z + v.w);
}

// pass-3 term sum for one float4 of e-values (8 VALU ops/element, no trans)
__device__ __forceinline__ float zsum4(float4 e, float4 pa, float rt, float c) {
    float gx = e.x * c, gy = e.y * c, gz = e.z * c, gw = e.w * c;
    float hx = fmaxf(gx * gx * gx, gx), hy = fmaxf(gy * gy * gy, gy);
    float hz = fmaxf(gz * gz * gz, gz), hw = fmaxf(gw * gw * gw, gw);
    float mx = fminf(pa.x * rt, 1.f),  my = fminf(pa.y * rt, 1.f);
    float mz = fminf(pa.z * rt, 1.f),  mw = fminf(pa.w * rt, 1.f);
    return (hx * mx + hy * my) + (hz * mz + hw * mw);
}

// One block: bincount via LDS atomics -> clamp -> powacc = acc^0.8 table.
__global__ __launch_bounds__(1024) void k_hist(const int* __restrict__ tg, int B,
                                               float* __restrict__ powacc) {
    __shared__ int hacc[CC];
    const int tid = threadIdx.x;
    #pragma unroll
    for (int k = 0; k < CC / 1024; ++k) hacc[tid + k * 1024] = 0;
    __syncthreads();
    const int4* __restrict__ tg4 = (const int4*)tg;
    for (int i = tid; i < B / 4; i += 1024) {
        int4 tv = tg4[i];
        atomicAdd(&hacc[tv.x], 1); atomicAdd(&hacc[tv.y], 1);
        atomicAdd(&hacc[tv.z], 1); atomicAdd(&hacc[tv.w], 1);
    }
    __syncthreads();
    #pragma unroll
    for (int k = 0; k < CC / 1024; ++k) {
        int i = tid + k * 1024;
        int a = hacc[i];
        if (a < 1) a = 1;                       // clamp(min=1)
        powacc[i] = __powf((float)a, 0.8f);     // acc^P
    }
}

__global__ __launch_bounds__(128, 8) void k_row(const float* __restrict__ outp,
                                                const int* __restrict__ tg,
                                                const float* __restrict__ powacc,
                                                float* __restrict__ nll) {
    __shared__ float2 red_ms[2];
    __shared__ float  red_z[2];

    const int b   = blockIdx.x;
    const int tid = threadIdx.x;          // 0..127
    const int w   = tid >> 6;             // 0..1
    const bool lane0 = (tid & 63) == 0;

    const float LOG_EPS = -4.605170185988091f;   // log(0.01)

    // scalar chain early (critical path to Koff / rt)
    const int   t    = tg[b];
    const float o_t  = outp[(size_t)b * CC + t];
    const float pa_t = powacc[t];

    const float4* __restrict__ src = (const float4*)(outp + (size_t)b * CC);
    const float4* __restrict__ pac = (const float4*)powacc;

    // ---- row into registers: 8 named float4s = 32 floats/thread ----
    float4 v0 = src[tid];
    float4 v1 = src[tid + 128];
    float4 v2 = src[tid + 256];
    float4 v3 = src[tid + 384];
    float4 v4 = src[tid + 512];
    float4 v5 = src[tid + 640];
    float4 v6 = src[tid + 768];
    float4 v7 = src[tid + 896];

    // ---- lane-local max (tree) ----
    float m0 = fmaxf(fmaxf(v0.x, v0.y), fmaxf(v0.z, v0.w));
    float m1 = fmaxf(fmaxf(v1.x, v1.y), fmaxf(v1.z, v1.w));
    float m2 = fmaxf(fmaxf(v2.x, v2.y), fmaxf(v2.z, v2.w));
    float m3 = fmaxf(fmaxf(v3.x, v3.y), fmaxf(v3.z, v3.w));
    float m4 = fmaxf(fmaxf(v4.x, v4.y), fmaxf(v4.z, v4.w));
    float m5 = fmaxf(fmaxf(v5.x, v5.y), fmaxf(v5.z, v5.w));
    float m6 = fmaxf(fmaxf(v6.x, v6.y), fmaxf(v6.z, v6.w));
    float m7 = fmaxf(fmaxf(v7.x, v7.y), fmaxf(v7.z, v7.w));
    const float mlane = fmaxf(fmaxf(fmaxf(m0, m1), fmaxf(m2, m3)),
                              fmaxf(fmaxf(m4, m5), fmaxf(m6, m7)));

    // wave max (DS pipe) overlaps upcoming exp burst (trans pipe)
    const float mw = wave_max(mlane);

    // e_j = exp(o_j - m_lane) in place; 4 independent partial sums
    float sA = exp4(v0, mlane) + exp4(v4, mlane);
    float sB = exp4(v1, mlane) + exp4(v5, mlane);
    float sC = exp4(v2, mlane) + exp4(v6, mlane);
    float sD = exp4(v3, mlane) + exp4(v7, mlane);

    // rebase once to wave max, then plain sum-reduce
    float S_w = wave_sum(((sA + sB) + (sC + sD)) * __expf(mlane - mw));
    if (lane0) red_ms[w] = make_float2(mw, S_w);
    __syncthreads();

    // cross-wave merge (2 waves)
    const float M = fmaxf(red_ms[0].x, red_ms[1].x);
    const float S = red_ms[0].y * __expf(red_ms[0].x - M)
                  + red_ms[1].y * __expf(red_ms[1].x - M);
    const float L       = M + __logf(S);                 // logsumexp
    const float logclip = fmaxf(o_t - L, LOG_EPS);       // log(max(p_t, EPS))
    const float Koff    = L + logclip;                   // g_j = exp(o_j - Koff)

    const float c  = __expf(mlane - Koff);               // g_j = e_j * c
    const float rt = __fdividef(1.0f, pa_t);

    // ---- pass 3: pure-VALU terms; pa loaded inline (L2-hot table) ----
    float z0 = zsum4(v0, pac[tid      ], rt, c) + zsum4(v4, pac[tid + 512], rt, c);
    float z1 = zsum4(v1, pac[tid + 128], rt, c) + zsum4(v5, pac[tid + 640], rt, c);
    float z2 = zsum4(v2, pac[tid + 256], rt, c) + zsum4(v6, pac[tid + 768], rt, c);
    float z3 = zsum4(v3, pac[tid + 384], rt, c) + zsum4(v7, pac[tid + 896], rt, c);
    float z  = wave_sum((z0 + z1) + (z2 + z3));
    if (lane0) red_z[w] = z;
    __syncthreads();

    if (tid == 0) {
        float Z = red_z[0] + red_z[1];
        nll[b] = Koff + __logf(Z) - o_t;       // plain store, no atomics
    }
}

// deterministic final mean: fixed strided partials + fixed tree
__global__ __launch_bounds__(1024) void k_reduce(const float* __restrict__ nll,
                                                 float* __restrict__ out, int B) {
    __shared__ float red[16];
    const int tid = threadIdx.x;
    const float4* __restrict__ n4 = (const float4*)nll;
    float s = 0.f;
    for (int i = tid; i < B / 4; i += 1024) {
        float4 v = n4[i];
        s += (v.x + v.y) + (v.z + v.w);
    }
    s = wave_sum(s);
    if ((tid & 63) == 0) red[tid >> 6] = s;
    __syncthreads();
    if (tid == 0) {
        float tsum = 0.f;
        #pragma unroll
        for (int k = 0; k < 16; ++k) tsum += red[k];
        out[0] = tsum / (float)B;
    }
}

extern "C" void kernel_launch(void* const* d_in, const int* in_sizes, int n_in,
                              void* d_out, int out_size, void* d_ws, size_t ws_size,
                              hipStream_t stream) {
    const float* outp = (const float*)d_in[0];   // [B, C] f32
    const int*   tg   = (const int*)d_in[1];     // [B] i32
    float*       out  = (float*)d_out;           // scalar f32

    const int B = in_sizes[1];                   // 8192 (C fixed at 4096)

    char*  ws     = (char*)d_ws;
    float* powacc = (float*)ws;                  // 16 KB
    float* nll    = (float*)(ws + 16384);        // B*4 = 32 KB

    k_hist  <<<1, 1024, 0, stream>>>(tg, B, powacc);
    k_row   <<<B, 128, 0, stream>>>(outp, tg, powacc, nll);
    k_reduce<<<1, 1024, 0, stream>>>(nll, out, B);
}

// Round 13
// 36.274 us; speedup vs baseline: 1.0323x; 1.0323x over previous
//
#include <hip/hip_runtime.h>
#include <math.h>

// SeesawLoss forward: B=8192 rows, C=4096 classes, P=0.8, Q=2.0, EPS=0.01
// Log-space algebra (no M2, no pass-3 transcendentals):
//   L    = logsumexp(o) ;  Koff = L + max(o_t - L, log(EPS))
//   g_j  = exp(o_j - Koff) (= sratio_j); exp(logit_j - Koff) = mit_j*max(g^3,g)
//   mit_j = min(powacc_j/powacc_t, 1)  [powacc = acc^0.8, monotone -> pred ok]
//   nll_b = Koff + log(Z) - o_t,  Z = sum_j mit_j*max(g_j^3, g_j)
// Range-safe: g <= 100 -> Z <= 4e9; Z >= g_t > 0. j==t term = g_t (mask-free).
//
// Topology this round: TWO rows per 256-thread block (8 floats/thread/row =
// 16 floats/thread total, same as best R11). Dual independent shuffle-reduce
// chains interleave (latency hiding); barriers amortize over 2 rows; powacc
// float4s loaded once, used by both rows. launch_bounds(256,7) -> <=72 VGPR
// (R8 lesson: hard-64 cap with ~64 live regs spills). NO grid-wide atomics
// (R4/R5: same-address atomic+fence from 8192 blocks ~670us across 8 XCDs).

#define CC 4096

__device__ __forceinline__ float wave_sum(float v) {
    #pragma unroll
    for (int o = 32; o > 0; o >>= 1) v += __shfl_xor(v, o, 64);
    return v;
}

// exp each component against lane max (in place), return component sum
__device__ __forceinline__ float exp4(float4& v, float m) {
    v.x = __expf(v.x - m); v.y = __expf(v.y - m);
    v.z = __expf(v.z - m); v.w = __expf(v.w - m);
    return (v.x + v.y) + (v.z + v.w);
}

// pass-3 term sum for one float4 of e-values (8 VALU ops/element, no trans)
__device__ __forceinline__ float zsum4(float4 e, float4 pa, float rt, float c) {
    float gx = e.x * c, gy = e.y * c, gz = e.z * c, gw = e.w * c;
    float hx = fmaxf(gx * gx * gx, gx), hy = fmaxf(gy * gy * gy, gy);
    float hz = fmaxf(gz * gz * gz, gz), hw = fmaxf(gw * gw * gw, gw);
    float mx = fminf(pa.x * rt, 1.f),  my = fminf(pa.y * rt, 1.f);
    float mz = fminf(pa.z * rt, 1.f),  mw = fminf(pa.w * rt, 1.f);
    return (hx * mx + hy * my) + (hz * mz + hw * mw);
}

// One block: bincount via LDS atomics -> clamp -> powacc = acc^0.8 table.
__global__ __launch_bounds__(1024) void k_hist(const int* __restrict__ tg, int B,
                                               float* __restrict__ powacc) {
    __shared__ int hacc[CC];
    const int tid = threadIdx.x;
    #pragma unroll
    for (int k = 0; k < CC / 1024; ++k) hacc[tid + k * 1024] = 0;
    __syncthreads();
    const int4* __restrict__ tg4 = (const int4*)tg;
    for (int i = tid; i < B / 4; i += 1024) {
        int4 tv = tg4[i];
        atomicAdd(&hacc[tv.x], 1); atomicAdd(&hacc[tv.y], 1);
        atomicAdd(&hacc[tv.z], 1); atomicAdd(&hacc[tv.w], 1);
    }
    __syncthreads();
    #pragma unroll
    for (int k = 0; k < CC / 1024; ++k) {
        int i = tid + k * 1024;
        int a = hacc[i];
        if (a < 1) a = 1;                       // clamp(min=1)
        powacc[i] = __powf((float)a, 0.8f);     // acc^P
    }
}

__global__ __launch_bounds__(256, 7) void k_row(const float* __restrict__ outp,
                                                const int* __restrict__ tg,
                                                const float* __restrict__ powacc,
                                                float* __restrict__ nll) {
    __shared__ float2 redA[4], redB[4];
    __shared__ float  rzA[4],  rzB[4];

    const int rA  = blockIdx.x * 2;
    const int rB  = rA + 1;
    const int tid = threadIdx.x;
    const int w   = tid >> 6;
    const bool lane0 = (tid & 63) == 0;

    const float LOG_EPS = -4.605170185988091f;   // log(0.01)

    // scalar chains early (critical path to Koff / rt)
    const int   tA = tg[rA],                  tB = tg[rB];
    const float o_tA = outp[(size_t)rA * CC + tA];
    const float o_tB = outp[(size_t)rB * CC + tB];
    const float pa_tA = powacc[tA],           pa_tB = powacc[tB];

    const float4* __restrict__ srcA = (const float4*)(outp + (size_t)rA * CC);
    const float4* __restrict__ srcB = (const float4*)(outp + (size_t)rB * CC);
    const float4* __restrict__ pac  = (const float4*)powacc;

    // ---- both rows into registers: 8 named float4s (rule #20) ----
    float4 a0 = srcA[tid];
    float4 a1 = srcA[tid + 256];
    float4 a2 = srcA[tid + 512];
    float4 a3 = srcA[tid + 768];
    float4 b0 = srcB[tid];
    float4 b1 = srcB[tid + 256];
    float4 b2 = srcB[tid + 512];
    float4 b3 = srcB[tid + 768];

    // ---- lane-local maxes ----
    float mA = fmaxf(fmaxf(fmaxf(a0.x, a0.y), fmaxf(a0.z, a0.w)),
                     fmaxf(fmaxf(a1.x, a1.y), fmaxf(a1.z, a1.w)));
    mA = fmaxf(mA, fmaxf(fmaxf(a2.x, a2.y), fmaxf(a2.z, a2.w)));
    mA = fmaxf(mA, fmaxf(fmaxf(a3.x, a3.y), fmaxf(a3.z, a3.w)));
    float mB = fmaxf(fmaxf(fmaxf(b0.x, b0.y), fmaxf(b0.z, b0.w)),
                     fmaxf(fmaxf(b1.x, b1.y), fmaxf(b1.z, b1.w)));
    mB = fmaxf(mB, fmaxf(fmaxf(b2.x, b2.y), fmaxf(b2.z, b2.w)));
    mB = fmaxf(mB, fmaxf(fmaxf(b3.x, b3.y), fmaxf(b3.z, b3.w)));

    // ---- dual wave-max (interleaved chains hide shfl latency) ----
    float mwA = mA, mwB = mB;
    #pragma unroll
    for (int o = 32; o > 0; o >>= 1) {
        mwA = fmaxf(mwA, __shfl_xor(mwA, o, 64));
        mwB = fmaxf(mwB, __shfl_xor(mwB, o, 64));
    }

    // ---- e = exp(o - m_lane) in place; lane sums ----
    float sA = (exp4(a0, mA) + exp4(a1, mA)) + (exp4(a2, mA) + exp4(a3, mA));
    float sB = (exp4(b0, mB) + exp4(b1, mB)) + (exp4(b2, mB) + exp4(b3, mB));

    // rebase to wave max; dual interleaved sum-reduce
    float SA = sA * __expf(mA - mwA);
    float SB = sB * __expf(mB - mwB);
    #pragma unroll
    for (int o = 32; o > 0; o >>= 1) {
        SA += __shfl_xor(SA, o, 64);
        SB += __shfl_xor(SB, o, 64);
    }
    if (lane0) { redA[w] = make_float2(mwA, SA); redB[w] = make_float2(mwB, SB); }
    __syncthreads();

    // cross-wave merges (uniform on all threads)
    const float MA = fmaxf(fmaxf(redA[0].x, redA[1].x), fmaxf(redA[2].x, redA[3].x));
    const float MB = fmaxf(fmaxf(redB[0].x, redB[1].x), fmaxf(redB[2].x, redB[3].x));
    const float SSA = redA[0].y * __expf(redA[0].x - MA)
                    + redA[1].y * __expf(redA[1].x - MA)
                    + redA[2].y * __expf(redA[2].x - MA)
                    + redA[3].y * __expf(redA[3].x - MA);
    const float SSB = redB[0].y * __expf(redB[0].x - MB)
                    + redB[1].y * __expf(redB[1].x - MB)
                    + redB[2].y * __expf(redB[2].x - MB)
                    + redB[3].y * __expf(redB[3].x - MB);
    const float LA = MA + __logf(SSA);
    const float LB = MB + __logf(SSB);
    const float KoffA = LA + fmaxf(o_tA - LA, LOG_EPS);
    const float KoffB = LB + fmaxf(o_tB - LB, LOG_EPS);
    const float cA = __expf(mA - KoffA), cB = __expf(mB - KoffB);
    const float rtA = __fdividef(1.0f, pa_tA);
    const float rtB = __fdividef(1.0f, pa_tB);

    // ---- pass 3: powacc loaded ONCE, used by both rows ----
    float zA, zB;
    {
        float4 p = pac[tid];
        zA = zsum4(a0, p, rtA, cA);  zB = zsum4(b0, p, rtB, cB);
    }
    {
        float4 p = pac[tid + 256];
        zA += zsum4(a1, p, rtA, cA); zB += zsum4(b1, p, rtB, cB);
    }
    {
        float4 p = pac[tid + 512];
        zA += zsum4(a2, p, rtA, cA); zB += zsum4(b2, p, rtB, cB);
    }
    {
        float4 p = pac[tid + 768];
        zA += zsum4(a3, p, rtA, cA); zB += zsum4(b3, p, rtB, cB);
    }
    #pragma unroll
    for (int o = 32; o > 0; o >>= 1) {
        zA += __shfl_xor(zA, o, 64);
        zB += __shfl_xor(zB, o, 64);
    }
    if (lane0) { rzA[w] = zA; rzB[w] = zB; }
    __syncthreads();

    if (tid == 0) {
        float Z = (rzA[0] + rzA[1]) + (rzA[2] + rzA[3]);
        nll[rA] = KoffA + __logf(Z) - o_tA;
    }
    if (tid == 64) {
        float Z = (rzB[0] + rzB[1]) + (rzB[2] + rzB[3]);
        nll[rB] = KoffB + __logf(Z) - o_tB;
    }
}

// deterministic final mean: fixed strided partials + fixed tree
__global__ __launch_bounds__(1024) void k_reduce(const float* __restrict__ nll,
                                                 float* __restrict__ out, int B) {
    __shared__ float red[16];
    const int tid = threadIdx.x;
    const float4* __restrict__ n4 = (const float4*)nll;
    float s = 0.f;
    for (int i = tid; i < B / 4; i += 1024) {
        float4 v = n4[i];
        s += (v.x + v.y) + (v.z + v.w);
    }
    s = wave_sum(s);
    if ((tid & 63) == 0) red[tid >> 6] = s;
    __syncthreads();
    if (tid == 0) {
        float tsum = 0.f;
        #pragma unroll
        for (int k = 0; k < 16; ++k) tsum += red[k];
        out[0] = tsum / (float)B;
    }
}

extern "C" void kernel_launch(void* const* d_in, const int* in_sizes, int n_in,
                              void* d_out, int out_size, void* d_ws, size_t ws_size,
                              hipStream_t stream) {
    const float* outp = (const float*)d_in[0];   // [B, C] f32
    const int*   tg   = (const int*)d_in[1];     // [B] i32
    float*       out  = (float*)d_out;           // scalar f32

    const int B = in_sizes[1];                   // 8192 (C fixed at 4096)

    char*  ws     = (char*)d_ws;
    float* powacc = (float*)ws;                  // 16 KB
    float* nll    = (float*)(ws + 16384);        // B*4 = 32 KB

    k_hist  <<<1, 1024, 0, stream>>>(tg, B, powacc);
    k_row   <<<B / 2, 256, 0, stream>>>(outp, tg, powacc, nll);
    k_reduce<<<1, 1024, 0, stream>>>(nll, out, B);
}